// Round 3
// baseline (2944.712 us; speedup 1.0000x reference)
//
#include <hip/hip_runtime.h>
#include <math.h>

// ---------------------------------------------------------------------------
// GPRGNN: z = sum_k temp[k] * A_hat^k (MLP(x)),  A_hat = D^-1/2 (A+I) D^-1/2
// Pipeline: deg histogram -> scan -> CSR(dst) -> dinv -> fused MLP -> 10x SpMM
// edge_index arrives as int32 (harness converts integer inputs to int32).
// ---------------------------------------------------------------------------

__global__ __launch_bounds__(256) void k_deg(const int* __restrict__ dst,
                                             int E, int N, int* __restrict__ deg) {
    int e = blockIdx.x * 256 + threadIdx.x;
    if (e < E) {
        int d = dst[e];
        if ((unsigned)d < (unsigned)N) atomicAdd(&deg[d], 1);
    }
}

// inclusive scan of 1024-chunks; writes per-chunk inclusive scans + chunk sums
__global__ __launch_bounds__(256) void k_scan1(const int* __restrict__ deg, int N,
                                               int* __restrict__ incl,
                                               int* __restrict__ bsum) {
    __shared__ int sd[256];
    int b = blockIdx.x, t = threadIdx.x;
    int base = b * 1024 + t * 4;
    int v0 = (base + 0 < N) ? deg[base + 0] : 0;
    int v1 = (base + 1 < N) ? deg[base + 1] : 0;
    int v2 = (base + 2 < N) ? deg[base + 2] : 0;
    int v3 = (base + 3 < N) ? deg[base + 3] : 0;
    int s1 = v0 + v1, s2 = s1 + v2, s3 = s2 + v3;
    sd[t] = s3;
    __syncthreads();
    for (int off = 1; off < 256; off <<= 1) {
        int val = (t >= off) ? sd[t - off] : 0;
        __syncthreads();
        sd[t] += val;
        __syncthreads();
    }
    int prev = (t > 0) ? sd[t - 1] : 0;
    if (base + 0 < N) incl[base + 0] = prev + v0;
    if (base + 1 < N) incl[base + 1] = prev + s1;
    if (base + 2 < N) incl[base + 2] = prev + s2;
    if (base + 3 < N) incl[base + 3] = prev + s3;
    if (t == 255) bsum[b] = sd[255];
}

// single-block exclusive scan of chunk sums (B <= 128)
__global__ __launch_bounds__(128) void k_scan2(const int* __restrict__ bsum, int B,
                                               int* __restrict__ boff) {
    __shared__ int sd[128];
    int t = threadIdx.x;
    sd[t] = (t < B) ? bsum[t] : 0;
    __syncthreads();
    for (int off = 1; off < 128; off <<= 1) {
        int val = (t >= off) ? sd[t - off] : 0;
        __syncthreads();
        sd[t] += val;
        __syncthreads();
    }
    if (t < B) boff[t] = (t > 0) ? sd[t - 1] : 0;
}

__global__ __launch_bounds__(256) void k_rowptr(const int* __restrict__ incl,
                                                const int* __restrict__ deg,
                                                const int* __restrict__ boff, int N,
                                                int* __restrict__ rowptr,
                                                int* __restrict__ cur) {
    int i = blockIdx.x * 256 + threadIdx.x;
    if (i < N) {
        int r = incl[i] - deg[i] + boff[i >> 10];
        rowptr[i] = r;
        cur[i] = r;
    }
}

__global__ __launch_bounds__(256) void k_dinv(const int* __restrict__ deg, int N,
                                              float* __restrict__ dinv) {
    int i = blockIdx.x * 256 + threadIdx.x;
    if (i < N) dinv[i] = 1.0f / sqrtf((float)(deg[i] + 1));  // +1 self-loop
}

__global__ __launch_bounds__(256) void k_fill(const int* __restrict__ src,
                                              const int* __restrict__ dst, int E,
                                              int N,
                                              int* __restrict__ cur,
                                              int* __restrict__ col) {
    int e = blockIdx.x * 256 + threadIdx.x;
    if (e < E) {
        int d = dst[e];
        int s = src[e];
        if ((unsigned)d < (unsigned)N && (unsigned)s < (unsigned)N) {
            int p = atomicAdd(&cur[d], 1);
            col[p] = s;
        }
    }
}

// Fused MLP: h = relu(x@W1^T+b1)@W2^T+b2 ; also z0 = temp[0]*h
// 64 nodes per block, 256 threads, 4x4 register blocking for GEMM1.
__global__ __launch_bounds__(256) void k_mlp(const float* __restrict__ x,
                                             const float* __restrict__ W1,
                                             const float* __restrict__ b1,
                                             const float* __restrict__ W2,
                                             const float* __restrict__ b2,
                                             const float* __restrict__ temp, int N,
                                             float* __restrict__ h,
                                             float* __restrict__ z) {
    __shared__ float xs[64][65];   // +1 pad: conflict-free row reads
    __shared__ float w1s[64][65];
    __shared__ float hr[64][65];
    __shared__ float w2s[40][65];
    __shared__ float ob[64 * 40];
    const int t = threadIdx.x;
    const int n0 = blockIdx.x * 64;
    for (int i = t; i < 64 * 40; i += 256) ob[i] = 0.f;
    const int tr = t >> 4, tc = t & 15;

    for (int hc = 0; hc < 4; ++hc) {  // 4 chunks of 64 hidden units
        float acc[4][4];
#pragma unroll
        for (int i = 0; i < 4; ++i)
#pragma unroll
            for (int j = 0; j < 4; ++j) acc[i][j] = 0.f;

        for (int k0 = 0; k0 < 512; k0 += 64) {
#pragma unroll
            for (int l = 0; l < 4; ++l) {
                int idx = t + l * 256;  // 0..1023
                int n = idx >> 4;       // 0..63
                int k4 = idx & 15;      // 0..15
                int gn = n0 + n;
                float4 v = make_float4(0.f, 0.f, 0.f, 0.f);
                if (gn < N) v = *(const float4*)&x[(size_t)gn * 512 + k0 + k4 * 4];
                xs[n][k4 * 4 + 0] = v.x;
                xs[n][k4 * 4 + 1] = v.y;
                xs[n][k4 * 4 + 2] = v.z;
                xs[n][k4 * 4 + 3] = v.w;
                float4 wv = *(const float4*)&W1[(size_t)(hc * 64 + n) * 512 + k0 + k4 * 4];
                w1s[n][k4 * 4 + 0] = wv.x;
                w1s[n][k4 * 4 + 1] = wv.y;
                w1s[n][k4 * 4 + 2] = wv.z;
                w1s[n][k4 * 4 + 3] = wv.w;
            }
            __syncthreads();
#pragma unroll
            for (int kk = 0; kk < 64; ++kk) {
                float a0 = xs[tr * 4 + 0][kk], a1 = xs[tr * 4 + 1][kk];
                float a2 = xs[tr * 4 + 2][kk], a3 = xs[tr * 4 + 3][kk];
                float c0 = w1s[tc * 4 + 0][kk], c1 = w1s[tc * 4 + 1][kk];
                float c2 = w1s[tc * 4 + 2][kk], c3 = w1s[tc * 4 + 3][kk];
                acc[0][0] += a0 * c0; acc[0][1] += a0 * c1; acc[0][2] += a0 * c2; acc[0][3] += a0 * c3;
                acc[1][0] += a1 * c0; acc[1][1] += a1 * c1; acc[1][2] += a1 * c2; acc[1][3] += a1 * c3;
                acc[2][0] += a2 * c0; acc[2][1] += a2 * c1; acc[2][2] += a2 * c2; acc[2][3] += a2 * c3;
                acc[3][0] += a3 * c0; acc[3][1] += a3 * c1; acc[3][2] += a3 * c2; acc[3][3] += a3 * c3;
            }
            __syncthreads();
        }
        // bias + relu -> hr
#pragma unroll
        for (int i = 0; i < 4; ++i)
#pragma unroll
            for (int j = 0; j < 4; ++j) {
                int hj = hc * 64 + tc * 4 + j;
                float v = acc[i][j] + b1[hj];
                hr[tr * 4 + i][tc * 4 + j] = v > 0.f ? v : 0.f;
            }
        // stage W2 chunk
        for (int i = t; i < 40 * 64; i += 256) {
            int f = i >> 6, hh = i & 63;
            w2s[f][hh] = W2[f * 256 + hc * 64 + hh];
        }
        __syncthreads();
        // ob[n][f] += hr[n][:] . w2s[f][:]
        {
            int n = t >> 2, fg = t & 3;
#pragma unroll
            for (int ff = 0; ff < 10; ++ff) {
                int f = fg * 10 + ff;
                float s = 0.f;
#pragma unroll
                for (int hh = 0; hh < 64; ++hh) s += hr[n][hh] * w2s[f][hh];
                ob[n * 40 + f] += s;
            }
        }
        __syncthreads();
    }
    // epilogue: h and z0 = temp[0]*h
    float t0 = temp[0];
    for (int i = t; i < 64 * 40; i += 256) {
        int n = i / 40, f = i % 40;
        int gn = n0 + n;
        if (gn < N) {
            float v = ob[i] + b2[f];
            h[(size_t)gn * 40 + f] = v;
            z[(size_t)gn * 40 + f] = t0 * v;
        }
    }
}

// one wave per dst node; lanes 0..39 own the 40 features
__global__ __launch_bounds__(256) void k_prop(const float* __restrict__ hin,
                                              float* __restrict__ hout,
                                              float* __restrict__ z,
                                              const int* __restrict__ rowptr,
                                              const int* __restrict__ deg,
                                              const int* __restrict__ col,
                                              const float* __restrict__ dinv,
                                              const float* __restrict__ temp, int k,
                                              int N) {
    int wave = (blockIdx.x * 256 + threadIdx.x) >> 6;
    int lane = threadIdx.x & 63;
    if (wave >= N) return;
    int d = wave;
    float dv = dinv[d];
    float tk = temp[k];
    int start = rowptr[d];
    int cnt = deg[d];
    float acc = 0.f;
    if (lane < 40) acc = dv * dv * hin[(size_t)d * 40 + lane];
    for (int e = 0; e < cnt; ++e) {
        int s = col[start + e];
        float w = dinv[s] * dv;
        if (lane < 40) acc += w * hin[(size_t)s * 40 + lane];
    }
    if (lane < 40) {
        hout[(size_t)d * 40 + lane] = acc;
        z[(size_t)d * 40 + lane] += tk * acc;
    }
}

extern "C" void kernel_launch(void* const* d_in, const int* in_sizes, int n_in,
                              void* d_out, int out_size, void* d_ws, size_t ws_size,
                              hipStream_t stream) {
    const float* x = (const float*)d_in[0];
    const int* ei = (const int*)d_in[1];   // int32 per harness contract
    const float* W1 = (const float*)d_in[2];
    const float* b1 = (const float*)d_in[3];
    const float* W2 = (const float*)d_in[4];
    const float* b2 = (const float*)d_in[5];
    const float* temp = (const float*)d_in[6];
    const int N = in_sizes[0] / 512;
    const int E = in_sizes[1] / 2;
    const int* srcp = ei;
    const int* dstp = ei + E;

    char* w = (char*)d_ws;
    size_t off = 0;
    auto alloc = [&](size_t b) {
        size_t o = off;
        off = (off + b + 255) & ~(size_t)255;
        return o;
    };
    float* h = (float*)(w + alloc((size_t)N * 40 * 4));
    float* hb = (float*)(w + alloc((size_t)N * 40 * 4));
    int* deg = (int*)(w + alloc((size_t)N * 4));
    int* incl = (int*)(w + alloc((size_t)N * 4));
    int* rowptr = (int*)(w + alloc((size_t)N * 4));
    int* cur = (int*)(w + alloc((size_t)N * 4));
    float* dinv = (float*)(w + alloc((size_t)N * 4));
    int* col = (int*)(w + alloc((size_t)E * 4));
    int* bsum = (int*)(w + alloc(4096));
    int* boff = (int*)(w + alloc(4096));
    (void)ws_size;

    hipMemsetAsync(deg, 0, (size_t)N * 4, stream);
    const int eb = (E + 255) / 256;
    const int nB = (N + 1023) / 1024;  // 98 chunks (<=128)
    const int nb = (N + 255) / 256;

    k_deg<<<eb, 256, 0, stream>>>(dstp, E, N, deg);
    k_scan1<<<nB, 256, 0, stream>>>(deg, N, incl, bsum);
    k_scan2<<<1, 128, 0, stream>>>(bsum, nB, boff);
    k_rowptr<<<nb, 256, 0, stream>>>(incl, deg, boff, N, rowptr, cur);
    k_dinv<<<nb, 256, 0, stream>>>(deg, N, dinv);
    k_fill<<<eb, 256, 0, stream>>>(srcp, dstp, E, N, cur, col);
    k_mlp<<<(N + 63) / 64, 256, 0, stream>>>(x, W1, b1, W2, b2, temp, N, h,
                                             (float*)d_out);
    const int pb = (N * 64 + 255) / 256;
    float* bufs[2] = {h, hb};
    for (int k = 1; k <= 10; ++k) {
        const float* hin = bufs[(k - 1) & 1];
        float* hout = bufs[k & 1];
        k_prop<<<pb, 256, 0, stream>>>(hin, hout, (float*)d_out, rowptr, deg, col,
                                       dinv, temp, k, N);
    }
}

// Round 4
// 1401.925 us; speedup vs baseline: 2.1005x; 2.1005x over previous
//
#include <hip/hip_runtime.h>
#include <math.h>

// ---------------------------------------------------------------------------
// GPRGNN: z = sum_k temp[k] * A_hat^k (MLP(x)),  A_hat = D^-1/2 (A+I) D^-1/2
// Build: deg histogram -> scan -> CSR(dst) + edge weights -> fused MFMA MLP
//        -> 10x gather SpMM.
// MLP GEMM1 uses split-bf16 (hi+lo) 3-product MFMA == fp32 accuracy.
// ---------------------------------------------------------------------------

typedef __attribute__((ext_vector_type(8))) short short8;
typedef __attribute__((ext_vector_type(4))) float f32x4;
typedef __attribute__((ext_vector_type(4))) unsigned short u16x4;

__device__ __forceinline__ unsigned short f2bf(float f) {
    unsigned u = __float_as_uint(f);
    u += 0x7FFF + ((u >> 16) & 1);   // RTN-even
    return (unsigned short)(u >> 16);
}
__device__ __forceinline__ float bf2f(unsigned short h) {
    return __uint_as_float(((unsigned)h) << 16);
}

__global__ __launch_bounds__(256) void k_deg(const int* __restrict__ dst,
                                             int E, int N, int* __restrict__ deg) {
    int e = blockIdx.x * 256 + threadIdx.x;
    if (e < E) {
        int d = dst[e];
        if ((unsigned)d < (unsigned)N) atomicAdd(&deg[d], 1);
    }
}

__global__ __launch_bounds__(256) void k_scan1(const int* __restrict__ deg, int N,
                                               int* __restrict__ incl,
                                               int* __restrict__ bsum) {
    __shared__ int sd[256];
    int b = blockIdx.x, t = threadIdx.x;
    int base = b * 1024 + t * 4;
    int v0 = (base + 0 < N) ? deg[base + 0] : 0;
    int v1 = (base + 1 < N) ? deg[base + 1] : 0;
    int v2 = (base + 2 < N) ? deg[base + 2] : 0;
    int v3 = (base + 3 < N) ? deg[base + 3] : 0;
    int s1 = v0 + v1, s2 = s1 + v2, s3 = s2 + v3;
    sd[t] = s3;
    __syncthreads();
    for (int off = 1; off < 256; off <<= 1) {
        int val = (t >= off) ? sd[t - off] : 0;
        __syncthreads();
        sd[t] += val;
        __syncthreads();
    }
    int prev = (t > 0) ? sd[t - 1] : 0;
    if (base + 0 < N) incl[base + 0] = prev + v0;
    if (base + 1 < N) incl[base + 1] = prev + s1;
    if (base + 2 < N) incl[base + 2] = prev + s2;
    if (base + 3 < N) incl[base + 3] = prev + s3;
    if (t == 255) bsum[b] = sd[255];
}

__global__ __launch_bounds__(128) void k_scan2(const int* __restrict__ bsum, int B,
                                               int* __restrict__ boff) {
    __shared__ int sd[128];
    int t = threadIdx.x;
    sd[t] = (t < B) ? bsum[t] : 0;
    __syncthreads();
    for (int off = 1; off < 128; off <<= 1) {
        int val = (t >= off) ? sd[t - off] : 0;
        __syncthreads();
        sd[t] += val;
        __syncthreads();
    }
    if (t < B) boff[t] = (t > 0) ? sd[t - 1] : 0;
}

__global__ __launch_bounds__(256) void k_rowptr(const int* __restrict__ incl,
                                                const int* __restrict__ deg,
                                                const int* __restrict__ boff, int N,
                                                int* __restrict__ rowptr,
                                                int* __restrict__ cur) {
    int i = blockIdx.x * 256 + threadIdx.x;
    if (i < N) {
        int r = incl[i] - deg[i] + boff[i >> 10];
        rowptr[i] = r;
        cur[i] = r;
    }
}

// dinv = (deg+1)^-1/2 ; wself = (deg+1)^-1  (self-loop weight dinv^2)
__global__ __launch_bounds__(256) void k_dinv(const int* __restrict__ deg, int N,
                                              float* __restrict__ dinv,
                                              float* __restrict__ wself) {
    int i = blockIdx.x * 256 + threadIdx.x;
    if (i < N) {
        float dd = (float)(deg[i] + 1);
        dinv[i] = 1.0f / sqrtf(dd);
        wself[i] = 1.0f / dd;
    }
}

// CSR fill + precomputed edge weight wnorm = dinv[src]*dinv[dst]
__global__ __launch_bounds__(256) void k_fill(const int* __restrict__ src,
                                              const int* __restrict__ dst, int E,
                                              int N, int* __restrict__ cur,
                                              int* __restrict__ col,
                                              float* __restrict__ wnorm,
                                              const float* __restrict__ dinv) {
    int e = blockIdx.x * 256 + threadIdx.x;
    if (e < E) {
        int d = dst[e];
        int s = src[e];
        if ((unsigned)d < (unsigned)N && (unsigned)s < (unsigned)N) {
            int p = atomicAdd(&cur[d], 1);
            col[p] = s;
            wnorm[p] = dinv[s] * dinv[d];
        }
    }
}

// ---------------------------------------------------------------------------
// Fused MLP: h = relu(x@W1^T+b1)@W2^T+b2 ; z0 = temp[0]*h
// GEMM1: split-bf16 MFMA (3 products), BM=128, BN=256(=HID), BK=64, 8 waves.
// GEMM2: fused fp32 epilogue via LDS (two 64-row passes).
// LDS plan (bytes):
//   K-loop:   [0,18432) A_hi 128x144B | [18432,36864) A_lo
//             [36864,73728) B_hi 256x144B | [73728,110592) B_lo
//   Epilogue: [0,66560) h1 64x260 fp32 | [66560,108160) W2 40x260 fp32
// ---------------------------------------------------------------------------
#define MLP_LDS 110592
__global__ __launch_bounds__(512, 2) void k_mlp_fused(
    const float* __restrict__ x, const float* __restrict__ W1,
    const float* __restrict__ b1, const float* __restrict__ W2,
    const float* __restrict__ b2, const float* __restrict__ temp, int N,
    float* __restrict__ h, float* __restrict__ z) {
    __shared__ __align__(16) char smem[MLP_LDS];
    const int t = threadIdx.x;
    const int lane = t & 63;
    const int wv = t >> 6;   // 0..7
    const int wr = wv >> 2;  // 0..1 : row half
    const int wc = wv & 3;   // 0..3 : col quarter
    const int l15 = lane & 15;
    const int kg = lane >> 4;  // 0..3
    const long long row0 = (long long)blockIdx.x * 128;

    f32x4 acc[4][4];
#pragma unroll
    for (int i = 0; i < 4; ++i)
#pragma unroll
        for (int j = 0; j < 4; ++j) acc[i][j] = (f32x4){0.f, 0.f, 0.f, 0.f};

    for (int kt = 0; kt < 8; ++kt) {
        __syncthreads();
        // stage A (x tile 128x64 fp32 -> bf16 hi/lo)
#pragma unroll
        for (int j = 0; j < 4; ++j) {
            int idx = j * 512 + t;
            int r = idx >> 4, k4 = idx & 15;
            long long gn = row0 + r;
            f32x4 v = (f32x4){0.f, 0.f, 0.f, 0.f};
            if (gn < N) v = *(const f32x4*)&x[gn * 512 + kt * 64 + k4 * 4];
            unsigned short h0 = f2bf(v.x), h1 = f2bf(v.y), h2 = f2bf(v.z), h3 = f2bf(v.w);
            unsigned short q0 = f2bf(v.x - bf2f(h0)), q1 = f2bf(v.y - bf2f(h1));
            unsigned short q2 = f2bf(v.z - bf2f(h2)), q3 = f2bf(v.w - bf2f(h3));
            *(u16x4*)(smem + r * 144 + k4 * 8) = (u16x4){h0, h1, h2, h3};
            *(u16x4*)(smem + 18432 + r * 144 + k4 * 8) = (u16x4){q0, q1, q2, q3};
        }
        // stage B (W1 tile 256x64 fp32 -> bf16 hi/lo)
#pragma unroll
        for (int j = 0; j < 8; ++j) {
            int idx = j * 512 + t;
            int hr = idx >> 4, k4 = idx & 15;
            f32x4 v = *(const f32x4*)&W1[hr * 512 + kt * 64 + k4 * 4];
            unsigned short h0 = f2bf(v.x), h1 = f2bf(v.y), h2 = f2bf(v.z), h3 = f2bf(v.w);
            unsigned short q0 = f2bf(v.x - bf2f(h0)), q1 = f2bf(v.y - bf2f(h1));
            unsigned short q2 = f2bf(v.z - bf2f(h2)), q3 = f2bf(v.w - bf2f(h3));
            *(u16x4*)(smem + 36864 + hr * 144 + k4 * 8) = (u16x4){h0, h1, h2, h3};
            *(u16x4*)(smem + 73728 + hr * 144 + k4 * 8) = (u16x4){q0, q1, q2, q3};
        }
        __syncthreads();
#pragma unroll
        for (int s = 0; s < 2; ++s) {
            short8 ah[4], al[4];
#pragma unroll
            for (int mf = 0; mf < 4; ++mf) {
                int r = wr * 64 + mf * 16 + l15;
                int off = r * 144 + s * 64 + kg * 16;
                ah[mf] = *(const short8*)(smem + off);
                al[mf] = *(const short8*)(smem + 18432 + off);
            }
#pragma unroll
            for (int nf = 0; nf < 4; ++nf) {
                int hr = wc * 64 + nf * 16 + l15;
                int off = 36864 + hr * 144 + s * 64 + kg * 16;
                short8 bh = *(const short8*)(smem + off);
                short8 bl = *(const short8*)(smem + 36864 + off);
#pragma unroll
                for (int mf = 0; mf < 4; ++mf) {
                    acc[mf][nf] = __builtin_amdgcn_mfma_f32_16x16x32_bf16(ah[mf], bh, acc[mf][nf], 0, 0, 0);
                    acc[mf][nf] = __builtin_amdgcn_mfma_f32_16x16x32_bf16(ah[mf], bl, acc[mf][nf], 0, 0, 0);
                    acc[mf][nf] = __builtin_amdgcn_mfma_f32_16x16x32_bf16(al[mf], bh, acc[mf][nf], 0, 0, 0);
                }
            }
        }
    }

    float b1v[4];
#pragma unroll
    for (int nf = 0; nf < 4; ++nf) b1v[nf] = b1[wc * 64 + nf * 16 + l15];
    const float t0 = temp[0];

    __syncthreads();  // all frag reads done; LDS repurposed
    // stage W2 (40x256 fp32, 260-float row pitch)
#pragma unroll
    for (int j = 0; j < 20; ++j) {
        int idx = j * 512 + t;  // 0..10239
        int f = idx >> 8, k = idx & 255;
        *(float*)(smem + 66560 + f * 1040 + k * 4) = W2[f * 256 + k];
    }
#pragma unroll
    for (int p = 0; p < 2; ++p) {
        if (p) __syncthreads();  // GEMM2 readers of pass 0 done before rewrite
        if (wr == p) {
#pragma unroll
            for (int mf = 0; mf < 4; ++mf)
#pragma unroll
                for (int nf = 0; nf < 4; ++nf)
#pragma unroll
                    for (int rg = 0; rg < 4; ++rg) {
                        int rl = mf * 16 + kg * 4 + rg;       // 0..63
                        int c = wc * 64 + nf * 16 + l15;      // 0..255
                        float vv = acc[mf][nf][rg] + b1v[nf];
                        vv = vv > 0.f ? vv : 0.f;
                        *(float*)(smem + rl * 1040 + c * 4) = vv;
                    }
        }
        __syncthreads();
        // GEMM2 on rows p*64 .. p*64+63 : out[n][f] = h1[n][:]·W2[f][:]
        int nl = t >> 3;         // 0..63
        int fb = (t & 7) * 5;    // 0..35
        float o0 = 0.f, o1 = 0.f, o2 = 0.f, o3 = 0.f, o4 = 0.f;
#pragma unroll 4
        for (int k4 = 0; k4 < 64; ++k4) {
            f32x4 hv = *(const f32x4*)(smem + nl * 1040 + k4 * 16);
            f32x4 w0 = *(const f32x4*)(smem + 66560 + (fb + 0) * 1040 + k4 * 16);
            f32x4 w1 = *(const f32x4*)(smem + 66560 + (fb + 1) * 1040 + k4 * 16);
            f32x4 w2 = *(const f32x4*)(smem + 66560 + (fb + 2) * 1040 + k4 * 16);
            f32x4 w3 = *(const f32x4*)(smem + 66560 + (fb + 3) * 1040 + k4 * 16);
            f32x4 w4 = *(const f32x4*)(smem + 66560 + (fb + 4) * 1040 + k4 * 16);
            o0 += hv.x * w0.x + hv.y * w0.y + hv.z * w0.z + hv.w * w0.w;
            o1 += hv.x * w1.x + hv.y * w1.y + hv.z * w1.z + hv.w * w1.w;
            o2 += hv.x * w2.x + hv.y * w2.y + hv.z * w2.z + hv.w * w2.w;
            o3 += hv.x * w3.x + hv.y * w3.y + hv.z * w3.z + hv.w * w3.w;
            o4 += hv.x * w4.x + hv.y * w4.y + hv.z * w4.z + hv.w * w4.w;
        }
        long long gn = row0 + p * 64 + nl;
        if (gn < N) {
            float ov[5] = {o0, o1, o2, o3, o4};
#pragma unroll
            for (int j = 0; j < 5; ++j) {
                float val = ov[j] + b2[fb + j];
                h[gn * 40 + fb + j] = val;
                z[gn * 40 + fb + j] = t0 * val;
            }
        }
        __syncthreads();
    }
}

// one wave per dst node; lanes 0..39 own the 40 features; unroll-4 gather
__global__ __launch_bounds__(256) void k_prop(const float* __restrict__ hin,
                                              float* __restrict__ hout,
                                              float* __restrict__ z,
                                              const int* __restrict__ rowptr,
                                              const int* __restrict__ deg,
                                              const int* __restrict__ col,
                                              const float* __restrict__ wnorm,
                                              const float* __restrict__ wself,
                                              const float* __restrict__ temp, int k,
                                              int N) {
    int wid = (blockIdx.x * 256 + threadIdx.x) >> 6;
    int lane = threadIdx.x & 63;
    if (wid >= N) return;
    const bool act = lane < 40;
    const size_t base = (size_t)wid * 40;
    int start = rowptr[wid];
    int cnt = deg[wid];
    float acc = 0.f;
    if (act) acc = wself[wid] * hin[base + lane];
    int e = 0;
    for (; e + 4 <= cnt; e += 4) {
        int s0 = col[start + e + 0];
        int s1 = col[start + e + 1];
        int s2 = col[start + e + 2];
        int s3 = col[start + e + 3];
        float w0 = wnorm[start + e + 0];
        float w1 = wnorm[start + e + 1];
        float w2 = wnorm[start + e + 2];
        float w3 = wnorm[start + e + 3];
        if (act) {
            float v0 = hin[(size_t)s0 * 40 + lane];
            float v1 = hin[(size_t)s1 * 40 + lane];
            float v2 = hin[(size_t)s2 * 40 + lane];
            float v3 = hin[(size_t)s3 * 40 + lane];
            acc += w0 * v0;
            acc += w1 * v1;
            acc += w2 * v2;
            acc += w3 * v3;
        }
    }
    for (; e < cnt; ++e) {
        int s = col[start + e];
        float w = wnorm[start + e];
        if (act) acc += w * hin[(size_t)s * 40 + lane];
    }
    if (act) {
        hout[base + lane] = acc;
        z[base + lane] += temp[k] * acc;
    }
}

extern "C" void kernel_launch(void* const* d_in, const int* in_sizes, int n_in,
                              void* d_out, int out_size, void* d_ws, size_t ws_size,
                              hipStream_t stream) {
    const float* x = (const float*)d_in[0];
    const int* ei = (const int*)d_in[1];  // int32 per harness contract
    const float* W1 = (const float*)d_in[2];
    const float* b1 = (const float*)d_in[3];
    const float* W2 = (const float*)d_in[4];
    const float* b2 = (const float*)d_in[5];
    const float* temp = (const float*)d_in[6];
    const int N = in_sizes[0] / 512;
    const int E = in_sizes[1] / 2;
    const int* srcp = ei;
    const int* dstp = ei + E;

    char* w = (char*)d_ws;
    size_t off = 0;
    auto alloc = [&](size_t b) {
        size_t o = off;
        off = (off + b + 255) & ~(size_t)255;
        return o;
    };
    float* h = (float*)(w + alloc((size_t)N * 40 * 4));
    float* hb = (float*)(w + alloc((size_t)N * 40 * 4));
    int* deg = (int*)(w + alloc((size_t)N * 4));
    int* incl = (int*)(w + alloc((size_t)N * 4));
    int* rowptr = (int*)(w + alloc((size_t)N * 4));
    int* cur = (int*)(w + alloc((size_t)N * 4));
    float* dinv = (float*)(w + alloc((size_t)N * 4));
    float* wself = (float*)(w + alloc((size_t)N * 4));
    int* col = (int*)(w + alloc((size_t)E * 4));
    float* wnorm = (float*)(w + alloc((size_t)E * 4));
    int* bsum = (int*)(w + alloc(4096));
    int* boff = (int*)(w + alloc(4096));
    (void)ws_size;

    hipMemsetAsync(deg, 0, (size_t)N * 4, stream);
    const int eb = (E + 255) / 256;
    const int nB = (N + 1023) / 1024;
    const int nb = (N + 255) / 256;

    k_deg<<<eb, 256, 0, stream>>>(dstp, E, N, deg);
    k_scan1<<<nB, 256, 0, stream>>>(deg, N, incl, bsum);
    k_scan2<<<1, 128, 0, stream>>>(bsum, nB, boff);
    k_rowptr<<<nb, 256, 0, stream>>>(incl, deg, boff, N, rowptr, cur);
    k_dinv<<<nb, 256, 0, stream>>>(deg, N, dinv, wself);
    k_fill<<<eb, 256, 0, stream>>>(srcp, dstp, E, N, cur, col, wnorm, dinv);

    k_mlp_fused<<<(N + 127) / 128, 512, 0, stream>>>(x, W1, b1, W2, b2, temp, N, h,
                                                     (float*)d_out);

    const int pb = (N * 64 + 255) / 256;
    float* bufs[2] = {h, hb};
    for (int k = 1; k <= 10; ++k) {
        const float* hin = bufs[(k - 1) & 1];
        float* hout = bufs[k & 1];
        k_prop<<<pb, 256, 0, stream>>>(hin, hout, (float*)d_out, rowptr, deg, col,
                                       wnorm, wself, temp, k, N);
    }
}

// Round 6
// 1381.522 us; speedup vs baseline: 2.1315x; 1.0148x over previous
//
#include <hip/hip_runtime.h>
#include <math.h>

// ---------------------------------------------------------------------------
// GPRGNN: z = sum_k temp[k] * A_hat^k (MLP(x)),  A_hat = D^-1/2 (A+I) D^-1/2
// deg -> scan -> CSR(dst)+wnorm -> W1 bf16 hi/lo prepack -> fused MFMA MLP
// (128x256 tile, B staged in 2 halves, 2 blocks/CU) -> 10x gather SpMM
// (6 nodes/wave, float4 lanes).
// ---------------------------------------------------------------------------

typedef __attribute__((ext_vector_type(8))) short short8;
typedef __attribute__((ext_vector_type(4))) float f32x4;
typedef __attribute__((ext_vector_type(4))) unsigned short u16x4;

__device__ __forceinline__ unsigned short f2bf(float f) {
    unsigned u = __float_as_uint(f);
    u += 0x7FFF + ((u >> 16) & 1);  // RTN-even
    return (unsigned short)(u >> 16);
}
__device__ __forceinline__ float bf2f(unsigned short h) {
    return __uint_as_float(((unsigned)h) << 16);
}

__global__ __launch_bounds__(256) void k_deg(const int* __restrict__ dst,
                                             int E, int N, int* __restrict__ deg) {
    int e = blockIdx.x * 256 + threadIdx.x;
    if (e < E) {
        int d = dst[e];
        if ((unsigned)d < (unsigned)N) atomicAdd(&deg[d], 1);
    }
}

__global__ __launch_bounds__(256) void k_scan1(const int* __restrict__ deg, int N,
                                               int* __restrict__ incl,
                                               int* __restrict__ bsum) {
    __shared__ int sd[256];
    int b = blockIdx.x, t = threadIdx.x;
    int base = b * 1024 + t * 4;
    int v0 = (base + 0 < N) ? deg[base + 0] : 0;
    int v1 = (base + 1 < N) ? deg[base + 1] : 0;
    int v2 = (base + 2 < N) ? deg[base + 2] : 0;
    int v3 = (base + 3 < N) ? deg[base + 3] : 0;
    int s1 = v0 + v1, s2 = s1 + v2, s3 = s2 + v3;
    sd[t] = s3;
    __syncthreads();
    for (int off = 1; off < 256; off <<= 1) {
        int val = (t >= off) ? sd[t - off] : 0;
        __syncthreads();
        sd[t] += val;
        __syncthreads();
    }
    int prev = (t > 0) ? sd[t - 1] : 0;
    if (base + 0 < N) incl[base + 0] = prev + v0;
    if (base + 1 < N) incl[base + 1] = prev + s1;
    if (base + 2 < N) incl[base + 2] = prev + s2;
    if (base + 3 < N) incl[base + 3] = prev + s3;
    if (t == 255) bsum[b] = sd[255];
}

__global__ __launch_bounds__(128) void k_scan2(const int* __restrict__ bsum, int B,
                                               int* __restrict__ boff) {
    __shared__ int sd[128];
    int t = threadIdx.x;
    sd[t] = (t < B) ? bsum[t] : 0;
    __syncthreads();
    for (int off = 1; off < 128; off <<= 1) {
        int val = (t >= off) ? sd[t - off] : 0;
        __syncthreads();
        sd[t] += val;
        __syncthreads();
    }
    if (t < B) boff[t] = (t > 0) ? sd[t - 1] : 0;
}

__global__ __launch_bounds__(256) void k_rowptr(const int* __restrict__ incl,
                                                const int* __restrict__ deg,
                                                const int* __restrict__ boff, int N,
                                                int* __restrict__ rowptr,
                                                int* __restrict__ cur) {
    int i = blockIdx.x * 256 + threadIdx.x;
    if (i < N) {
        int r = incl[i] - deg[i] + boff[i >> 10];
        rowptr[i] = r;
        cur[i] = r;
    }
}

__global__ __launch_bounds__(256) void k_dinv(const int* __restrict__ deg, int N,
                                              float* __restrict__ dinv,
                                              float* __restrict__ wself) {
    int i = blockIdx.x * 256 + threadIdx.x;
    if (i < N) {
        float dd = (float)(deg[i] + 1);
        dinv[i] = 1.0f / sqrtf(dd);
        wself[i] = 1.0f / dd;
    }
}

__global__ __launch_bounds__(256) void k_fill(const int* __restrict__ src,
                                              const int* __restrict__ dst, int E,
                                              int N, int* __restrict__ cur,
                                              int* __restrict__ col,
                                              float* __restrict__ wnorm,
                                              const float* __restrict__ dinv) {
    int e = blockIdx.x * 256 + threadIdx.x;
    if (e < E) {
        int d = dst[e];
        int s = src[e];
        if ((unsigned)d < (unsigned)N && (unsigned)s < (unsigned)N) {
            int p = atomicAdd(&cur[d], 1);
            col[p] = s;
            wnorm[p] = dinv[s] * dinv[d];
        }
    }
}

// Pre-split W1 (256x512 fp32) into bf16 hi/lo, packed per K-tile and hid-half:
// u16x4 unit index = kt*4096 + hc*2048 + r*16 + k4  (r in 0..127 within half)
// holds W1[hc*128+r][kt*64 + k4*4 .. +3].
__global__ __launch_bounds__(256) void k_w1split(const float* __restrict__ W1,
                                                 u16x4* __restrict__ W1h_p,
                                                 u16x4* __restrict__ W1l_p) {
    int id = blockIdx.x * 256 + threadIdx.x;  // 0..32767
    if (id >= 32768) return;
    int kt = id >> 12;
    int hc = (id >> 11) & 1;
    int r = (id >> 4) & 127;
    int k4 = id & 15;
    int hid = hc * 128 + r;
    f32x4 v = *(const f32x4*)&W1[(size_t)hid * 512 + kt * 64 + k4 * 4];
    unsigned short h0 = f2bf(v.x), h1 = f2bf(v.y), h2 = f2bf(v.z), h3 = f2bf(v.w);
    unsigned short q0 = f2bf(v.x - bf2f(h0)), q1 = f2bf(v.y - bf2f(h1));
    unsigned short q2 = f2bf(v.z - bf2f(h2)), q3 = f2bf(v.w - bf2f(h3));
    W1h_p[id] = (u16x4){h0, h1, h2, h3};
    W1l_p[id] = (u16x4){q0, q1, q2, q3};
}

// ---------------------------------------------------------------------------
// Fused MLP: h = relu(x@W1^T+b1)@W2^T+b2 ; z0 = temp[0]*h
// BM=128, HID=256 (staged in 2 halves of 128), BK=64, 8 waves (2x4).
// LDS 73,728 B -> 2 blocks/CU.
//   K-loop:   [0,18432) A_hi 128x144B | [18432,36864) A_lo
//             [36864,55296) B_hi 128x144B | [55296,73728) B_lo
//   Epilogue: [0,16640) h1 16x1040B | [16640,58240) W2 40x1040B
// ---------------------------------------------------------------------------
__global__ __launch_bounds__(512, 2) void k_mlp_fused(
    const float* __restrict__ x, const u16x4* __restrict__ W1h_p,
    const u16x4* __restrict__ W1l_p, const float* __restrict__ b1,
    const float* __restrict__ W2, const float* __restrict__ b2,
    const float* __restrict__ temp, int N, float* __restrict__ h,
    float* __restrict__ z) {
    __shared__ __align__(16) char smem[73728];
    const int t = threadIdx.x;
    const int lane = t & 63;
    const int wv = t >> 6;   // 0..7
    const int wr = wv >> 2;  // 0..1 row half (64 rows)
    const int wc = wv & 3;   // 0..3 col slice (32 cols per B-half)
    const int l15 = lane & 15;
    const int kg = lane >> 4;  // 0..3
    const long long row0 = (long long)blockIdx.x * 128;

    f32x4 acc[4][4];  // [mf][hc*2+nfl]
#pragma unroll
    for (int i = 0; i < 4; ++i)
#pragma unroll
        for (int j = 0; j < 4; ++j) acc[i][j] = (f32x4){0.f, 0.f, 0.f, 0.f};

    for (int kt = 0; kt < 8; ++kt) {
        const u16x4* Bh = W1h_p + (size_t)kt * 4096;
        const u16x4* Bl = W1l_p + (size_t)kt * 4096;
        __syncthreads();
        // stage A: x tile 128x64 fp32 -> bf16 hi/lo
#pragma unroll
        for (int j = 0; j < 4; ++j) {
            int idx = j * 512 + t;
            int r = idx >> 4, k4 = idx & 15;
            long long gn = row0 + r;
            f32x4 v = (f32x4){0.f, 0.f, 0.f, 0.f};
            if (gn < N) v = *(const f32x4*)&x[gn * 512 + kt * 64 + k4 * 4];
            unsigned short h0 = f2bf(v.x), h1 = f2bf(v.y), h2 = f2bf(v.z), h3 = f2bf(v.w);
            unsigned short q0 = f2bf(v.x - bf2f(h0)), q1 = f2bf(v.y - bf2f(h1));
            unsigned short q2 = f2bf(v.z - bf2f(h2)), q3 = f2bf(v.w - bf2f(h3));
            *(u16x4*)(smem + r * 144 + k4 * 8) = (u16x4){h0, h1, h2, h3};
            *(u16x4*)(smem + 18432 + r * 144 + k4 * 8) = (u16x4){q0, q1, q2, q3};
        }
        // stage B half 0 (prepacked bf16, pure copy)
#pragma unroll
        for (int j = 0; j < 4; ++j) {
            int idx = j * 512 + t;  // 0..2047
            int r = idx >> 4, k4 = idx & 15;
            *(u16x4*)(smem + 36864 + r * 144 + k4 * 8) = Bh[idx];
            *(u16x4*)(smem + 55296 + r * 144 + k4 * 8) = Bl[idx];
        }
        __syncthreads();
#pragma unroll
        for (int hc = 0; hc < 2; ++hc) {
            if (hc == 1) {
                __syncthreads();  // MFMA half0 done reading B
#pragma unroll
                for (int j = 0; j < 4; ++j) {
                    int idx = j * 512 + t;
                    int r = idx >> 4, k4 = idx & 15;
                    *(u16x4*)(smem + 36864 + r * 144 + k4 * 8) = Bh[2048 + idx];
                    *(u16x4*)(smem + 55296 + r * 144 + k4 * 8) = Bl[2048 + idx];
                }
                __syncthreads();
            }
#pragma unroll
            for (int s = 0; s < 2; ++s) {
                short8 ah[4], al[4];
#pragma unroll
                for (int mf = 0; mf < 4; ++mf) {
                    int r = wr * 64 + mf * 16 + l15;
                    int off = r * 144 + s * 64 + kg * 16;
                    ah[mf] = *(const short8*)(smem + off);
                    al[mf] = *(const short8*)(smem + 18432 + off);
                }
#pragma unroll
                for (int nfl = 0; nfl < 2; ++nfl) {
                    int br = wc * 32 + nfl * 16 + l15;  // 0..127 within half
                    int off = 36864 + br * 144 + s * 64 + kg * 16;
                    short8 bh = *(const short8*)(smem + off);
                    short8 bl = *(const short8*)(smem + 18432 + off);
#pragma unroll
                    for (int mf = 0; mf < 4; ++mf) {
                        acc[mf][hc * 2 + nfl] = __builtin_amdgcn_mfma_f32_16x16x32_bf16(
                            ah[mf], bh, acc[mf][hc * 2 + nfl], 0, 0, 0);
                        acc[mf][hc * 2 + nfl] = __builtin_amdgcn_mfma_f32_16x16x32_bf16(
                            ah[mf], bl, acc[mf][hc * 2 + nfl], 0, 0, 0);
                        acc[mf][hc * 2 + nfl] = __builtin_amdgcn_mfma_f32_16x16x32_bf16(
                            al[mf], bh, acc[mf][hc * 2 + nfl], 0, 0, 0);
                    }
                }
            }
        }
    }

    // bias values per acc column slot
    float b1v[4];
#pragma unroll
    for (int nf4 = 0; nf4 < 4; ++nf4)
        b1v[nf4] = b1[(nf4 >> 1) * 128 + wc * 32 + (nf4 & 1) * 16 + l15];
    const float t0 = temp[0];

    __syncthreads();  // all K-loop LDS reads done; repurpose LDS
    // stage W2: 40x256 fp32, pitch 260 floats (1040 B)
#pragma unroll
    for (int j = 0; j < 20; ++j) {
        int idx = j * 512 + t;  // 0..10239
        int f = idx >> 8, k = idx & 255;
        *(float*)(smem + 16640 + f * 1040 + k * 4) = W2[f * 256 + k];
    }
    // 8 passes of 16 rows
#pragma unroll
    for (int p = 0; p < 8; ++p) {
        if (p) __syncthreads();  // prev pass GEMM2 reads done
        if (wr == (p >> 2)) {
            const int mf = p & 3;
#pragma unroll
            for (int nf4 = 0; nf4 < 4; ++nf4)
#pragma unroll
                for (int rg = 0; rg < 4; ++rg) {
                    int rl = kg * 4 + rg;  // 0..15
                    int c = (nf4 >> 1) * 128 + wc * 32 + (nf4 & 1) * 16 + l15;
                    float vv = acc[mf][nf4][rg] + b1v[nf4];
                    vv = vv > 0.f ? vv : 0.f;
                    *(float*)(smem + rl * 1040 + c * 4) = vv;
                }
        }
        __syncthreads();
        // GEMM2: rows p*16..p*16+15, out[n][f] = h1[n][:] . W2[f][:]
        int nl = t >> 5;   // 0..15
        int fi = t & 31;   // f = fi (0..31) and fi+32 if fi<8
        float o0 = 0.f, o1 = 0.f;
#pragma unroll 4
        for (int k4 = 0; k4 < 64; ++k4) {
            f32x4 hv = *(const f32x4*)(smem + nl * 1040 + k4 * 16);
            f32x4 w0 = *(const f32x4*)(smem + 16640 + fi * 1040 + k4 * 16);
            o0 += hv.x * w0.x + hv.y * w0.y + hv.z * w0.z + hv.w * w0.w;
            if (fi < 8) {
                f32x4 w1 = *(const f32x4*)(smem + 16640 + (fi + 32) * 1040 + k4 * 16);
                o1 += hv.x * w1.x + hv.y * w1.y + hv.z * w1.z + hv.w * w1.w;
            }
        }
        long long gn = row0 + p * 16 + nl;
        if (gn < N) {
            float v0 = o0 + b2[fi];
            h[gn * 40 + fi] = v0;
            z[gn * 40 + fi] = t0 * v0;
            if (fi < 8) {
                float v1 = o1 + b2[fi + 32];
                h[gn * 40 + fi + 32] = v1;
                z[gn * 40 + fi + 32] = t0 * v1;
            }
        }
    }
}

// 6 nodes per wave; 10-lane groups, each lane owns a float4 of the 40 feats
__global__ __launch_bounds__(256) void k_prop(const float* __restrict__ hin,
                                              float* __restrict__ hout,
                                              float* __restrict__ z,
                                              const int* __restrict__ rowptr,
                                              const int* __restrict__ deg,
                                              const int* __restrict__ col,
                                              const float* __restrict__ wnorm,
                                              const float* __restrict__ wself,
                                              const float* __restrict__ temp, int k,
                                              int N) {
    int wvg = (blockIdx.x * 256 + threadIdx.x) >> 6;
    int lane = threadIdx.x & 63;
    int g = lane / 10;
    int q = lane - g * 10;  // 0..9
    int d = wvg * 6 + g;
    const bool act = (g < 6) && (d < N);
    f32x4 acc = (f32x4){0.f, 0.f, 0.f, 0.f};
    int start = 0, cnt = 0;
    size_t base = 0;
    if (act) {
        base = (size_t)d * 40 + q * 4;
        start = rowptr[d];
        cnt = deg[d];
        acc = wself[d] * (*(const f32x4*)&hin[base]);
    }
    int e = 0;
    for (; e + 2 <= cnt; e += 2) {
        int s0 = col[start + e];
        int s1 = col[start + e + 1];
        float w0 = wnorm[start + e];
        float w1 = wnorm[start + e + 1];
        f32x4 v0 = *(const f32x4*)&hin[(size_t)s0 * 40 + q * 4];
        f32x4 v1 = *(const f32x4*)&hin[(size_t)s1 * 40 + q * 4];
        acc += w0 * v0;
        acc += w1 * v1;
    }
    if (e < cnt) {
        int s0 = col[start + e];
        float w0 = wnorm[start + e];
        acc += w0 * (*(const f32x4*)&hin[(size_t)s0 * 40 + q * 4]);
    }
    if (act) {
        *(f32x4*)&hout[base] = acc;
        f32x4 zz = *(const f32x4*)&z[base];
        zz += temp[k] * acc;
        *(f32x4*)&z[base] = zz;
    }
}

extern "C" void kernel_launch(void* const* d_in, const int* in_sizes, int n_in,
                              void* d_out, int out_size, void* d_ws, size_t ws_size,
                              hipStream_t stream) {
    const float* x = (const float*)d_in[0];
    const int* ei = (const int*)d_in[1];  // int32 per harness contract
    const float* W1 = (const float*)d_in[2];
    const float* b1 = (const float*)d_in[3];
    const float* W2 = (const float*)d_in[4];
    const float* b2 = (const float*)d_in[5];
    const float* temp = (const float*)d_in[6];
    const int N = in_sizes[0] / 512;
    const int E = in_sizes[1] / 2;
    const int* srcp = ei;
    const int* dstp = ei + E;

    char* w = (char*)d_ws;
    size_t off = 0;
    auto alloc = [&](size_t b) {
        size_t o = off;
        off = (off + b + 255) & ~(size_t)255;
        return o;
    };
    float* h = (float*)(w + alloc((size_t)N * 40 * 4));
    float* hb = (float*)(w + alloc((size_t)N * 40 * 4));
    int* deg = (int*)(w + alloc((size_t)N * 4));
    int* incl = (int*)(w + alloc((size_t)N * 4));
    int* rowptr = (int*)(w + alloc((size_t)N * 4));
    int* cur = (int*)(w + alloc((size_t)N * 4));
    float* dinv = (float*)(w + alloc((size_t)N * 4));
    float* wself = (float*)(w + alloc((size_t)N * 4));
    int* col = (int*)(w + alloc((size_t)E * 4));
    float* wnorm = (float*)(w + alloc((size_t)E * 4));
    u16x4* W1h_p = (u16x4*)(w + alloc(32768 * 8));
    u16x4* W1l_p = (u16x4*)(w + alloc(32768 * 8));
    int* bsum = (int*)(w + alloc(4096));
    int* boff = (int*)(w + alloc(4096));
    (void)ws_size;

    hipMemsetAsync(deg, 0, (size_t)N * 4, stream);
    const int eb = (E + 255) / 256;
    const int nB = (N + 1023) / 1024;
    const int nb = (N + 255) / 256;

    k_deg<<<eb, 256, 0, stream>>>(dstp, E, N, deg);
    k_scan1<<<nB, 256, 0, stream>>>(deg, N, incl, bsum);
    k_scan2<<<1, 128, 0, stream>>>(bsum, nB, boff);
    k_rowptr<<<nb, 256, 0, stream>>>(incl, deg, boff, N, rowptr, cur);
    k_dinv<<<nb, 256, 0, stream>>>(deg, N, dinv, wself);
    k_fill<<<eb, 256, 0, stream>>>(srcp, dstp, E, N, cur, col, wnorm, dinv);
    k_w1split<<<128, 256, 0, stream>>>(W1, W1h_p, W1l_p);

    k_mlp_fused<<<(N + 127) / 128, 512, 0, stream>>>(x, W1h_p, W1l_p, b1, W2, b2,
                                                     temp, N, h, (float*)d_out);

    const int waves = (N + 5) / 6;
    const int pb = (waves * 64 + 255) / 256;
    float* bufs[2] = {h, hb};
    for (int k = 1; k <= 10; ++k) {
        const float* hin = bufs[(k - 1) & 1];
        float* hout = bufs[k & 1];
        k_prop<<<pb, 256, 0, stream>>>(hin, hout, (float*)d_out, rowptr, deg, col,
                                       wnorm, wself, temp, k, N);
    }
}

// Round 7
// 1010.048 us; speedup vs baseline: 2.9154x; 1.3678x over previous
//
#include <hip/hip_runtime.h>
#include <math.h>

// ---------------------------------------------------------------------------
// GPRGNN: z = sum_k temp[k] * A_hat^k (MLP(x)),  A_hat = D^-1/2 (A+I) D^-1/2
// deg -> scan -> CSR(dst)+packed edge(col,w) -> W1 bf16 hi/lo prepack ->
// fused MFMA MLP (R4 structure: 128x256 tile, 2 barriers/kt, B pure-copy) ->
// 10x gather SpMM on fp16 h (80B rows, int2 edge meta, unroll 4).
// ---------------------------------------------------------------------------

typedef __attribute__((ext_vector_type(8))) short short8;
typedef __attribute__((ext_vector_type(4))) float f32x4;
typedef __attribute__((ext_vector_type(4))) unsigned short u16x4;
typedef __attribute__((ext_vector_type(4))) _Float16 f16x4;

__device__ __forceinline__ unsigned short f2bf(float f) {
    unsigned u = __float_as_uint(f);
    u += 0x7FFF + ((u >> 16) & 1);  // RTN-even
    return (unsigned short)(u >> 16);
}
__device__ __forceinline__ float bf2f(unsigned short h) {
    return __uint_as_float(((unsigned)h) << 16);
}

__global__ __launch_bounds__(256) void k_deg(const int* __restrict__ dst,
                                             int E, int N, int* __restrict__ deg) {
    int e = blockIdx.x * 256 + threadIdx.x;
    if (e < E) {
        int d = dst[e];
        if ((unsigned)d < (unsigned)N) atomicAdd(&deg[d], 1);
    }
}

__global__ __launch_bounds__(256) void k_scan1(const int* __restrict__ deg, int N,
                                               int* __restrict__ incl,
                                               int* __restrict__ bsum) {
    __shared__ int sd[256];
    int b = blockIdx.x, t = threadIdx.x;
    int base = b * 1024 + t * 4;
    int v0 = (base + 0 < N) ? deg[base + 0] : 0;
    int v1 = (base + 1 < N) ? deg[base + 1] : 0;
    int v2 = (base + 2 < N) ? deg[base + 2] : 0;
    int v3 = (base + 3 < N) ? deg[base + 3] : 0;
    int s1 = v0 + v1, s2 = s1 + v2, s3 = s2 + v3;
    sd[t] = s3;
    __syncthreads();
    for (int off = 1; off < 256; off <<= 1) {
        int val = (t >= off) ? sd[t - off] : 0;
        __syncthreads();
        sd[t] += val;
        __syncthreads();
    }
    int prev = (t > 0) ? sd[t - 1] : 0;
    if (base + 0 < N) incl[base + 0] = prev + v0;
    if (base + 1 < N) incl[base + 1] = prev + s1;
    if (base + 2 < N) incl[base + 2] = prev + s2;
    if (base + 3 < N) incl[base + 3] = prev + s3;
    if (t == 255) bsum[b] = sd[255];
}

__global__ __launch_bounds__(128) void k_scan2(const int* __restrict__ bsum, int B,
                                               int* __restrict__ boff) {
    __shared__ int sd[128];
    int t = threadIdx.x;
    sd[t] = (t < B) ? bsum[t] : 0;
    __syncthreads();
    for (int off = 1; off < 128; off <<= 1) {
        int val = (t >= off) ? sd[t - off] : 0;
        __syncthreads();
        sd[t] += val;
        __syncthreads();
    }
    if (t < B) boff[t] = (t > 0) ? sd[t - 1] : 0;
}

__global__ __launch_bounds__(256) void k_rowptr(const int* __restrict__ incl,
                                                const int* __restrict__ deg,
                                                const int* __restrict__ boff, int N,
                                                int* __restrict__ rowptr,
                                                int* __restrict__ cur) {
    int i = blockIdx.x * 256 + threadIdx.x;
    if (i < N) {
        int r = incl[i] - deg[i] + boff[i >> 10];
        rowptr[i] = r;
        cur[i] = r;
    }
}

__global__ __launch_bounds__(256) void k_dinv(const int* __restrict__ deg, int N,
                                              float* __restrict__ dinv,
                                              float* __restrict__ wself) {
    int i = blockIdx.x * 256 + threadIdx.x;
    if (i < N) {
        float dd = (float)(deg[i] + 1);
        dinv[i] = 1.0f / sqrtf(dd);
        wself[i] = 1.0f / dd;
    }
}

// CSR fill; packed edge meta: ew[p] = {src, bits(dinv[src]*dinv[dst])}
__global__ __launch_bounds__(256) void k_fill(const int* __restrict__ src,
                                              const int* __restrict__ dst, int E,
                                              int N, int* __restrict__ cur,
                                              int2* __restrict__ ew,
                                              const float* __restrict__ dinv) {
    int e = blockIdx.x * 256 + threadIdx.x;
    if (e < E) {
        int d = dst[e];
        int s = src[e];
        if ((unsigned)d < (unsigned)N && (unsigned)s < (unsigned)N) {
            int p = atomicAdd(&cur[d], 1);
            ew[p] = make_int2(s, __float_as_int(dinv[s] * dinv[d]));
        }
    }
}

// Pre-split W1 (256x512 fp32) into bf16 hi/lo, packed per K-tile:
// u16x4 unit index = kt*4096 + r*16 + k4 (r in 0..255)
// holds W1[r][kt*64 + k4*4 .. +3].
__global__ __launch_bounds__(256) void k_w1split(const float* __restrict__ W1,
                                                 u16x4* __restrict__ W1h_p,
                                                 u16x4* __restrict__ W1l_p) {
    int id = blockIdx.x * 256 + threadIdx.x;  // 0..32767
    if (id >= 32768) return;
    int kt = id >> 12;
    int r = (id >> 4) & 255;
    int k4 = id & 15;
    f32x4 v = *(const f32x4*)&W1[(size_t)r * 512 + kt * 64 + k4 * 4];
    unsigned short h0 = f2bf(v.x), h1 = f2bf(v.y), h2 = f2bf(v.z), h3 = f2bf(v.w);
    unsigned short q0 = f2bf(v.x - bf2f(h0)), q1 = f2bf(v.y - bf2f(h1));
    unsigned short q2 = f2bf(v.z - bf2f(h2)), q3 = f2bf(v.w - bf2f(h3));
    W1h_p[id] = (u16x4){h0, h1, h2, h3};
    W1l_p[id] = (u16x4){q0, q1, q2, q3};
}

// ---------------------------------------------------------------------------
// Fused MLP (R4 structure): h = relu(x@W1^T+b1)@W2^T+b2 ; z0 = temp[0]*h
// BM=128, BN=256(=HID), BK=64, 8 waves (2x4), 2 barriers/kt.
// B staged by pure 16B copies from prepacked W1 (no per-block conversion).
// LDS plan (bytes):
//   K-loop:   [0,18432) A_hi 128x144B | [18432,36864) A_lo
//             [36864,73728) B_hi 256x144B | [73728,110592) B_lo
//   Epilogue: [0,66560) h1 64x1040B | [66560,108160) W2 40x1040B
// h written as fp16 (for the propagation phase); z stays fp32.
// ---------------------------------------------------------------------------
#define MLP_LDS 110592
__global__ __launch_bounds__(512, 2) void k_mlp_fused(
    const float* __restrict__ x, const u16x4* __restrict__ W1h_p,
    const u16x4* __restrict__ W1l_p, const float* __restrict__ b1,
    const float* __restrict__ W2, const float* __restrict__ b2,
    const float* __restrict__ temp, int N, _Float16* __restrict__ h,
    float* __restrict__ z) {
    __shared__ __align__(16) char smem[MLP_LDS];
    const int t = threadIdx.x;
    const int lane = t & 63;
    const int wv = t >> 6;   // 0..7
    const int wr = wv >> 2;  // 0..1 : row half (64 rows)
    const int wc = wv & 3;   // 0..3 : col quarter (64 cols)
    const int l15 = lane & 15;
    const int kg = lane >> 4;  // 0..3
    const long long row0 = (long long)blockIdx.x * 128;

    f32x4 acc[4][4];
#pragma unroll
    for (int i = 0; i < 4; ++i)
#pragma unroll
        for (int j = 0; j < 4; ++j) acc[i][j] = (f32x4){0.f, 0.f, 0.f, 0.f};

    for (int kt = 0; kt < 8; ++kt) {
        const short8* BhP = (const short8*)(W1h_p + (size_t)kt * 4096);  // 2048x16B
        const short8* BlP = (const short8*)(W1l_p + (size_t)kt * 4096);
        __syncthreads();
        // stage A: x tile 128x64 fp32 -> bf16 hi/lo (converted once per element)
#pragma unroll
        for (int j = 0; j < 4; ++j) {
            int idx = j * 512 + t;
            int r = idx >> 4, k4 = idx & 15;
            long long gn = row0 + r;
            f32x4 v = (f32x4){0.f, 0.f, 0.f, 0.f};
            if (gn < N) v = *(const f32x4*)&x[gn * 512 + kt * 64 + k4 * 4];
            unsigned short h0 = f2bf(v.x), h1 = f2bf(v.y), h2 = f2bf(v.z), h3 = f2bf(v.w);
            unsigned short q0 = f2bf(v.x - bf2f(h0)), q1 = f2bf(v.y - bf2f(h1));
            unsigned short q2 = f2bf(v.z - bf2f(h2)), q3 = f2bf(v.w - bf2f(h3));
            *(u16x4*)(smem + r * 144 + k4 * 8) = (u16x4){h0, h1, h2, h3};
            *(u16x4*)(smem + 18432 + r * 144 + k4 * 8) = (u16x4){q0, q1, q2, q3};
        }
        // stage B: prepacked bf16, pure 16B copies
#pragma unroll
        for (int j = 0; j < 4; ++j) {
            int idx = j * 512 + t;  // 0..2047
            int r = idx >> 3, u = idx & 7;
            *(short8*)(smem + 36864 + r * 144 + u * 16) = BhP[idx];
            *(short8*)(smem + 73728 + r * 144 + u * 16) = BlP[idx];
        }
        __syncthreads();
#pragma unroll
        for (int s = 0; s < 2; ++s) {
            short8 ah[4], al[4];
#pragma unroll
            for (int mf = 0; mf < 4; ++mf) {
                int r = wr * 64 + mf * 16 + l15;
                int off = r * 144 + s * 64 + kg * 16;
                ah[mf] = *(const short8*)(smem + off);
                al[mf] = *(const short8*)(smem + 18432 + off);
            }
#pragma unroll
            for (int nf = 0; nf < 4; ++nf) {
                int hr = wc * 64 + nf * 16 + l15;
                int off = 36864 + hr * 144 + s * 64 + kg * 16;
                short8 bh = *(const short8*)(smem + off);
                short8 bl = *(const short8*)(smem + 36864 + off);
#pragma unroll
                for (int mf = 0; mf < 4; ++mf) {
                    acc[mf][nf] = __builtin_amdgcn_mfma_f32_16x16x32_bf16(ah[mf], bh, acc[mf][nf], 0, 0, 0);
                    acc[mf][nf] = __builtin_amdgcn_mfma_f32_16x16x32_bf16(ah[mf], bl, acc[mf][nf], 0, 0, 0);
                    acc[mf][nf] = __builtin_amdgcn_mfma_f32_16x16x32_bf16(al[mf], bh, acc[mf][nf], 0, 0, 0);
                }
            }
        }
    }

    float b1v[4];
#pragma unroll
    for (int nf = 0; nf < 4; ++nf) b1v[nf] = b1[wc * 64 + nf * 16 + l15];
    const float t0 = temp[0];

    __syncthreads();  // all K-loop LDS reads done; repurpose LDS
    // stage W2: 40x256 fp32, pitch 260 floats (1040 B)
#pragma unroll
    for (int j = 0; j < 20; ++j) {
        int idx = j * 512 + t;  // 0..10239
        int f = idx >> 8, k = idx & 255;
        *(float*)(smem + 66560 + f * 1040 + k * 4) = W2[f * 256 + k];
    }
    // 2 passes of 64 rows
#pragma unroll
    for (int p = 0; p < 2; ++p) {
        if (p) __syncthreads();  // pass-0 GEMM2 reads done before rewrite
        if (wr == p) {
#pragma unroll
            for (int mf = 0; mf < 4; ++mf)
#pragma unroll
                for (int nf = 0; nf < 4; ++nf)
#pragma unroll
                    for (int rg = 0; rg < 4; ++rg) {
                        int rl = mf * 16 + kg * 4 + rg;   // 0..63
                        int c = wc * 64 + nf * 16 + l15;  // 0..255
                        float vv = acc[mf][nf][rg] + b1v[nf];
                        vv = vv > 0.f ? vv : 0.f;
                        *(float*)(smem + rl * 1040 + c * 4) = vv;
                    }
        }
        __syncthreads();
        // GEMM2: rows p*64..p*64+63, out[n][f] = h1[n][:] . W2[f][:]
        int nl = t >> 3;       // 0..63
        int fb = (t & 7) * 5;  // 0,5,...,35
        float o0 = 0.f, o1 = 0.f, o2 = 0.f, o3 = 0.f, o4 = 0.f;
#pragma unroll 4
        for (int k4 = 0; k4 < 64; ++k4) {
            f32x4 hv = *(const f32x4*)(smem + nl * 1040 + k4 * 16);
            f32x4 w0 = *(const f32x4*)(smem + 66560 + (fb + 0) * 1040 + k4 * 16);
            f32x4 w1 = *(const f32x4*)(smem + 66560 + (fb + 1) * 1040 + k4 * 16);
            f32x4 w2 = *(const f32x4*)(smem + 66560 + (fb + 2) * 1040 + k4 * 16);
            f32x4 w3 = *(const f32x4*)(smem + 66560 + (fb + 3) * 1040 + k4 * 16);
            f32x4 w4 = *(const f32x4*)(smem + 66560 + (fb + 4) * 1040 + k4 * 16);
            o0 += hv.x * w0.x + hv.y * w0.y + hv.z * w0.z + hv.w * w0.w;
            o1 += hv.x * w1.x + hv.y * w1.y + hv.z * w1.z + hv.w * w1.w;
            o2 += hv.x * w2.x + hv.y * w2.y + hv.z * w2.z + hv.w * w2.w;
            o3 += hv.x * w3.x + hv.y * w3.y + hv.z * w3.z + hv.w * w3.w;
            o4 += hv.x * w4.x + hv.y * w4.y + hv.z * w4.z + hv.w * w4.w;
        }
        long long gn = row0 + p * 64 + nl;
        if (gn < N) {
            float ov[5] = {o0, o1, o2, o3, o4};
#pragma unroll
            for (int j = 0; j < 5; ++j) {
                float val = ov[j] + b2[fb + j];
                h[gn * 40 + fb + j] = (_Float16)val;
                z[gn * 40 + fb + j] = t0 * val;
            }
        }
        __syncthreads();
    }
}

// 6 nodes per wave; 10-lane groups; lane owns 4 fp16 feats (8B); unroll 4
__global__ __launch_bounds__(256) void k_prop(const _Float16* __restrict__ hin,
                                              _Float16* __restrict__ hout,
                                              float* __restrict__ z,
                                              const int* __restrict__ rowptr,
                                              const int* __restrict__ deg,
                                              const int2* __restrict__ ew,
                                              const float* __restrict__ wself,
                                              const float* __restrict__ temp, int k,
                                              int N) {
    int wvg = (blockIdx.x * 256 + threadIdx.x) >> 6;
    int lane = threadIdx.x & 63;
    int g = lane / 10;
    int q = lane - g * 10;  // 0..9
    int d = wvg * 6 + g;
    const bool act = (g < 6) && (d < N);
    f32x4 acc = (f32x4){0.f, 0.f, 0.f, 0.f};
    int start = 0, cnt = 0;
    size_t base = 0;
    if (act) {
        base = (size_t)d * 40 + q * 4;
        start = rowptr[d];
        cnt = deg[d];
        f16x4 sv = *(const f16x4*)&hin[base];
        float ws = wself[d];
        acc = (f32x4){ws * (float)sv.x, ws * (float)sv.y, ws * (float)sv.z,
                      ws * (float)sv.w};
    }
    int e = 0;
    for (; e + 4 <= cnt; e += 4) {
        int2 e0 = ew[start + e + 0];
        int2 e1 = ew[start + e + 1];
        int2 e2 = ew[start + e + 2];
        int2 e3 = ew[start + e + 3];
        f16x4 v0 = *(const f16x4*)&hin[(size_t)e0.x * 40 + q * 4];
        f16x4 v1 = *(const f16x4*)&hin[(size_t)e1.x * 40 + q * 4];
        f16x4 v2 = *(const f16x4*)&hin[(size_t)e2.x * 40 + q * 4];
        f16x4 v3 = *(const f16x4*)&hin[(size_t)e3.x * 40 + q * 4];
        float w0 = __int_as_float(e0.y), w1 = __int_as_float(e1.y);
        float w2 = __int_as_float(e2.y), w3 = __int_as_float(e3.y);
        acc.x += w0 * (float)v0.x + w1 * (float)v1.x + w2 * (float)v2.x + w3 * (float)v3.x;
        acc.y += w0 * (float)v0.y + w1 * (float)v1.y + w2 * (float)v2.y + w3 * (float)v3.y;
        acc.z += w0 * (float)v0.z + w1 * (float)v1.z + w2 * (float)v2.z + w3 * (float)v3.z;
        acc.w += w0 * (float)v0.w + w1 * (float)v1.w + w2 * (float)v2.w + w3 * (float)v3.w;
    }
    for (; e < cnt; ++e) {
        int2 e0 = ew[start + e];
        f16x4 v0 = *(const f16x4*)&hin[(size_t)e0.x * 40 + q * 4];
        float w0 = __int_as_float(e0.y);
        acc.x += w0 * (float)v0.x;
        acc.y += w0 * (float)v0.y;
        acc.z += w0 * (float)v0.z;
        acc.w += w0 * (float)v0.w;
    }
    if (act) {
        f16x4 o;
        o.x = (_Float16)acc.x;
        o.y = (_Float16)acc.y;
        o.z = (_Float16)acc.z;
        o.w = (_Float16)acc.w;
        *(f16x4*)&hout[base] = o;
        f32x4 zz = *(const f32x4*)&z[base];
        float tk = temp[k];
        zz.x += tk * acc.x;
        zz.y += tk * acc.y;
        zz.z += tk * acc.z;
        zz.w += tk * acc.w;
        *(f32x4*)&z[base] = zz;
    }
}

extern "C" void kernel_launch(void* const* d_in, const int* in_sizes, int n_in,
                              void* d_out, int out_size, void* d_ws, size_t ws_size,
                              hipStream_t stream) {
    const float* x = (const float*)d_in[0];
    const int* ei = (const int*)d_in[1];  // int32 per harness contract
    const float* W1 = (const float*)d_in[2];
    const float* b1 = (const float*)d_in[3];
    const float* W2 = (const float*)d_in[4];
    const float* b2 = (const float*)d_in[5];
    const float* temp = (const float*)d_in[6];
    const int N = in_sizes[0] / 512;
    const int E = in_sizes[1] / 2;
    const int* srcp = ei;
    const int* dstp = ei + E;

    char* w = (char*)d_ws;
    size_t off = 0;
    auto alloc = [&](size_t b) {
        size_t o = off;
        off = (off + b + 255) & ~(size_t)255;
        return o;
    };
    _Float16* h = (_Float16*)(w + alloc((size_t)N * 40 * 2));
    _Float16* hb = (_Float16*)(w + alloc((size_t)N * 40 * 2));
    int* deg = (int*)(w + alloc((size_t)N * 4));
    int* incl = (int*)(w + alloc((size_t)N * 4));
    int* rowptr = (int*)(w + alloc((size_t)N * 4));
    int* cur = (int*)(w + alloc((size_t)N * 4));
    float* dinv = (float*)(w + alloc((size_t)N * 4));
    float* wself = (float*)(w + alloc((size_t)N * 4));
    int2* ew = (int2*)(w + alloc((size_t)E * 8));
    u16x4* W1h_p = (u16x4*)(w + alloc(32768 * 8));
    u16x4* W1l_p = (u16x4*)(w + alloc(32768 * 8));
    int* bsum = (int*)(w + alloc(4096));
    int* boff = (int*)(w + alloc(4096));
    (void)ws_size;

    hipMemsetAsync(deg, 0, (size_t)N * 4, stream);
    const int eb = (E + 255) / 256;
    const int nB = (N + 1023) / 1024;
    const int nb = (N + 255) / 256;

    k_deg<<<eb, 256, 0, stream>>>(dstp, E, N, deg);
    k_scan1<<<nB, 256, 0, stream>>>(deg, N, incl, bsum);
    k_scan2<<<1, 128, 0, stream>>>(bsum, nB, boff);
    k_rowptr<<<nb, 256, 0, stream>>>(incl, deg, boff, N, rowptr, cur);
    k_dinv<<<nb, 256, 0, stream>>>(deg, N, dinv, wself);
    k_fill<<<eb, 256, 0, stream>>>(srcp, dstp, E, N, cur, ew, dinv);
    k_w1split<<<128, 256, 0, stream>>>(W1, W1h_p, W1l_p);

    k_mlp_fused<<<(N + 127) / 128, 512, 0, stream>>>(x, W1h_p, W1l_p, b1, W2, b2,
                                                     temp, N, h, (float*)d_out);

    const int waves = (N + 5) / 6;
    const int pb = (waves * 64 + 255) / 256;
    _Float16* bufs[2] = {h, hb};
    for (int k = 1; k <= 10; ++k) {
        const _Float16* hin = bufs[(k - 1) & 1];
        _Float16* hout = bufs[k & 1];
        k_prop<<<pb, 256, 0, stream>>>(hin, hout, (float*)d_out, rowptr, deg, ew,
                                       wself, temp, k, N);
    }
}